// Round 9
// baseline (177.662 us; speedup 1.0000x reference)
//
#include <hip/hip_runtime.h>
#include <stdint.h>

#define DEV static __device__ __forceinline__

typedef __bf16 bf16x8 __attribute__((ext_vector_type(8)));
typedef unsigned short u16x8 __attribute__((ext_vector_type(8)));
typedef float f32x4 __attribute__((ext_vector_type(4)));

// ---- bf16 helpers (RNE) ----
DEV unsigned short f2bf(float f) {
    unsigned int u = __builtin_bit_cast(unsigned int, f);
    u = (u + 0x7FFFu + ((u >> 16) & 1u)) >> 16;
    return (unsigned short)u;
}
DEV float bf2f(unsigned short h) {
    unsigned int u = ((unsigned int)h) << 16;
    return __builtin_bit_cast(float, u);
}

// ---- async global->LDS, 16B per lane (wave-uniform LDS base + lane*16) ----
DEV void gload_lds16(const unsigned short* g, unsigned short* l) {
    __builtin_amdgcn_global_load_lds(
        (const __attribute__((address_space(1))) unsigned int*)g,
        (__attribute__((address_space(3))) unsigned int*)l, 16, 0, 0);
}

// ===================== fused cvt + weight transpose =====================
// grid 5120: [0,4096) x fp32->bf16; [4096,5120) W transpose 64x64 tiles
// (256 blocks/matrix). LDS 16.6KB -> high occupancy for both branches.
__global__ __launch_bounds__(256) void k_prep0(
    const float* __restrict__ x, const float* __restrict__ Wq,
    const float* __restrict__ Wk, const float* __restrict__ Wv,
    const float* __restrict__ Wo, unsigned short* __restrict__ xb,
    unsigned short* __restrict__ Wqkvt, unsigned short* __restrict__ Wot) {
    __shared__ float tile[64][65];
    int bid = blockIdx.x, tid = threadIdx.x;
    if (bid < 4096) {
        int i = bid * 256 + tid;
        float4 v = ((const float4*)x)[i];
        ushort4 o;
        o.x = f2bf(v.x); o.y = f2bf(v.y); o.z = f2bf(v.z); o.w = f2bf(v.w);
        ((ushort4*)xb)[i] = o;
    } else {
        int idx = bid - 4096;
        int z = idx >> 8, rem = idx & 255;
        const float* W = (z == 0) ? Wq : (z == 1) ? Wk : (z == 2) ? Wv : Wo;
        int k0 = (rem & 15) * 64, n0 = (rem >> 4) * 64;
        int tx = tid & 63, ty = tid >> 6;
        #pragma unroll
        for (int r = 0; r < 64; r += 4)
            tile[ty + r][tx] = W[(size_t)(k0 + ty + r) * 1024 + n0 + tx];
        __syncthreads();
        #pragma unroll
        for (int r = 0; r < 64; r += 4) {
            float v = tile[tx][ty + r];           // = W[k0+tx][n0+ty+r]
            int n = n0 + ty + r, k = k0 + tx;
            if (z < 3) Wqkvt[(size_t)(z * 1024 + n) * 1024 + k] = f2bf(v);
            else       Wot[(size_t)n * 1024 + k] = f2bf(v);
        }
    }
}

// ===================== beta = sigmoid(x @ Wb + bb) =====================
// grid 1024 x 256: one row per wave. WbT staged in BF16 (32KB LDS -> 4 blocks/CU).
__global__ __launch_bounds__(256) void k_beta(const float* __restrict__ x,
                                              const float* __restrict__ Wb,
                                              const float* __restrict__ bb,
                                              float* __restrict__ beta) {
    __shared__ unsigned short WbT[16 * 1024];
    int tid = threadIdx.x;
    #pragma unroll
    for (int j = 0; j < 16; j++) {
        int idx4 = tid + 256 * j;
        float4 v = ((const float4*)Wb)[idx4];
        int i = idx4 >> 2;
        int h0 = (idx4 & 3) * 4;
        WbT[(h0 + 0) * 1024 + (i ^ ((h0 + 0) << 2))] = f2bf(v.x);
        WbT[(h0 + 1) * 1024 + (i ^ ((h0 + 1) << 2))] = f2bf(v.y);
        WbT[(h0 + 2) * 1024 + (i ^ ((h0 + 2) << 2))] = f2bf(v.z);
        WbT[(h0 + 3) * 1024 + (i ^ ((h0 + 3) << 2))] = f2bf(v.w);
    }
    __syncthreads();
    int w = tid >> 6, lane = tid & 63;
    int row = blockIdx.x * 4 + w;
    const float* xr = x + (size_t)row * 1024;
    float acc[16] = {};
    #pragma unroll
    for (int k = 0; k < 16; k++) {
        int i = lane + 64 * k;
        float xv = xr[i];
        #pragma unroll
        for (int h = 0; h < 16; h++)
            acc[h] += xv * bf2f(WbT[h * 1024 + (i ^ (h << 2))]);
    }
    #pragma unroll
    for (int h = 0; h < 16; h++) {
        #pragma unroll
        for (int m = 32; m; m >>= 1) acc[h] += __shfl_xor(acc[h], m, 64);
    }
    if (lane == 0) {
        #pragma unroll
        for (int h = 0; h < 16; h++)
            beta[row * 16 + h] = 1.f / (1.f + __expf(-(acc[h] + bb[h])));
    }
}

// ===================== QKV GEMM: 128x128 tile, BK=64, gload_lds staging =====================
__global__ __launch_bounds__(256) void k_gemm_qkv(const unsigned short* __restrict__ A,
                                                  const unsigned short* __restrict__ Bt,
                                                  unsigned short* __restrict__ C) {
    __shared__ unsigned short As[128 * 64];
    __shared__ unsigned short Bs[128 * 64];
    int m0 = blockIdx.x * 128, n0 = blockIdx.y * 128;
    int tid = threadIdx.x;
    int w = tid >> 6, lane = tid & 63, g = lane >> 4, ln = lane & 15;
    int wr = w >> 1, wc = w & 1;
    f32x4 acc[4][4] = {};
    for (int k0 = 0; k0 < 1024; k0 += 64) {
        #pragma unroll
        for (int cc = 0; cc < 4; cc++) {
            int base = (w * 4 + cc) * 64;          // wave-uniform chunk base (0..1023)
            int chunk = base + lane;
            int row = chunk >> 3, ps = chunk & 7;
            int sl = (ps - (row >> 1)) & 7;        // inverse swizzle on source
            gload_lds16(A + (size_t)(m0 + row) * 1024 + k0 + sl * 8, &As[base * 8]);
            gload_lds16(Bt + (size_t)(n0 + row) * 1024 + k0 + sl * 8, &Bs[base * 8]);
        }
        __syncthreads();
        #pragma unroll
        for (int s = 0; s < 2; s++) {
            bf16x8 af[4], bfr[4];
            #pragma unroll
            for (int mi = 0; mi < 4; mi++) {
                int row = wr * 64 + mi * 16 + ln;
                int ps = (s * 4 + g + (row >> 1)) & 7;
                af[mi] = *(const bf16x8*)(&As[row * 64 + ps * 8]);
            }
            #pragma unroll
            for (int ni = 0; ni < 4; ni++) {
                int row = wc * 64 + ni * 16 + ln;
                int ps = (s * 4 + g + (row >> 1)) & 7;
                bfr[ni] = *(const bf16x8*)(&Bs[row * 64 + ps * 8]);
            }
            #pragma unroll
            for (int mi = 0; mi < 4; mi++)
                #pragma unroll
                for (int ni = 0; ni < 4; ni++)
                    acc[mi][ni] = __builtin_amdgcn_mfma_f32_16x16x32_bf16(
                        af[mi], bfr[ni], acc[mi][ni], 0, 0, 0);
        }
        __syncthreads();
    }
    #pragma unroll
    for (int mi = 0; mi < 4; mi++)
        #pragma unroll
        for (int ni = 0; ni < 4; ni++)
            #pragma unroll
            for (int r = 0; r < 4; r++) {
                int row = m0 + wr * 64 + mi * 16 + g * 4 + r;
                int col = n0 + wc * 64 + ni * 16 + ln;
                C[(size_t)row * 3072 + col] = f2bf(acc[mi][ni][r]);
            }
}

// ===================== out GEMM: 128x64 tile, BK=64, fp32 out =====================
__global__ __launch_bounds__(256) void k_gemm_out(const unsigned short* __restrict__ A,
                                                  const unsigned short* __restrict__ Bt,
                                                  float* __restrict__ C) {
    __shared__ unsigned short As[128 * 64];
    __shared__ unsigned short Bs[64 * 64];
    int m0 = blockIdx.x * 128, n0 = blockIdx.y * 64;
    int tid = threadIdx.x;
    int w = tid >> 6, lane = tid & 63, g = lane >> 4, ln = lane & 15;
    int wr = w >> 1, wc = w & 1;
    f32x4 acc[4][2] = {};
    for (int k0 = 0; k0 < 1024; k0 += 64) {
        #pragma unroll
        for (int i = 0; i < 6; i++) {
            int base = w * 384 + i * 64;           // wave-uniform
            int chunk = base + lane;
            if (base < 1024) {                     // A chunks 0..1023
                int row = chunk >> 3, ps = chunk & 7;
                int sl = (ps - (row >> 1)) & 7;
                gload_lds16(A + (size_t)(m0 + row) * 1024 + k0 + sl * 8, &As[base * 8]);
            } else {                               // B chunks 0..511
                int bc = chunk - 1024;
                int row = bc >> 3, ps = bc & 7;
                int sl = (ps - (row >> 1)) & 7;
                gload_lds16(Bt + (size_t)(n0 + row) * 1024 + k0 + sl * 8, &Bs[(base - 1024) * 8]);
            }
        }
        __syncthreads();
        #pragma unroll
        for (int s = 0; s < 2; s++) {
            bf16x8 af[4], bfr[2];
            #pragma unroll
            for (int mi = 0; mi < 4; mi++) {
                int row = wr * 64 + mi * 16 + ln;
                int ps = (s * 4 + g + (row >> 1)) & 7;
                af[mi] = *(const bf16x8*)(&As[row * 64 + ps * 8]);
            }
            #pragma unroll
            for (int ni = 0; ni < 2; ni++) {
                int row = wc * 32 + ni * 16 + ln;
                int ps = (s * 4 + g + (row >> 1)) & 7;
                bfr[ni] = *(const bf16x8*)(&Bs[row * 64 + ps * 8]);
            }
            #pragma unroll
            for (int mi = 0; mi < 4; mi++)
                #pragma unroll
                for (int ni = 0; ni < 2; ni++)
                    acc[mi][ni] = __builtin_amdgcn_mfma_f32_16x16x32_bf16(
                        af[mi], bfr[ni], acc[mi][ni], 0, 0, 0);
        }
        __syncthreads();
    }
    #pragma unroll
    for (int mi = 0; mi < 4; mi++)
        #pragma unroll
        for (int ni = 0; ni < 2; ni++)
            #pragma unroll
            for (int r = 0; r < 4; r++) {
                int row = m0 + wr * 64 + mi * 16 + g * 4 + r;
                int col = n0 + wc * 32 + ni * 16 + ln;
                C[(size_t)row * 1024 + col] = acc[mi][ni][r];
            }
}

// ===================== chunked linear attention =====================
DEV int vswz(int dh, int ks) { return (ks ^ (dh & 7) ^ ((dh >> 3) & 7)) & 7; }

__global__ __launch_bounds__(256) void k_state(const unsigned short* __restrict__ QKV,
                                               const float* __restrict__ beta,
                                               unsigned short* __restrict__ Mbuf) {
    __shared__ unsigned short Kt[64 * 64];  // [dk][t], vswz, scaled by beta/||k||
    __shared__ unsigned short Vt[64 * 64];  // [dv][t], vswz
    int c = blockIdx.x, bh = blockIdx.y;
    int b = bh >> 4, h = bh & 15;
    int tid = threadIdx.x, w = tid >> 6, lane = tid & 63, g = lane >> 4, ln = lane & 15;
    int row0 = b * 2048 + c * 64;
    const unsigned short* Kg = QKV + 1024;
    const unsigned short* Vg = QKV + 2048;
    #pragma unroll
    for (int cc = 0; cc < 2; cc++) {
        int ci = tid + cc * 256;
        int r = ci >> 3, sl = ci & 7;   // 8 consecutive lanes share key row r
        uint4 kd = *(const uint4*)(Kg + (size_t)(row0 + r) * 3072 + h * 64 + sl * 8);
        uint4 vd = *(const uint4*)(Vg + (size_t)(row0 + r) * 3072 + h * 64 + sl * 8);
        union { uint4 q; unsigned short s[8]; } uk, uv;
        uk.q = kd; uv.q = vd;
        float ssk = 0.f;
        #pragma unroll
        for (int i = 0; i < 8; i++) { float v = bf2f(uk.s[i]); ssk += v * v; }
        ssk += __shfl_xor(ssk, 1, 64);
        ssk += __shfl_xor(ssk, 2, 64);
        ssk += __shfl_xor(ssk, 4, 64);
        float ksc = beta[(row0 + r) * 16 + h] / fmaxf(sqrtf(ssk), 1e-12f);
        #pragma unroll
        for (int i = 0; i < 8; i++) {
            int dh = sl * 8 + i;
            int off = dh * 64 + vswz(dh, r >> 3) * 8 + (r & 7);
            Kt[off] = f2bf(bf2f(uk.s[i]) * ksc);
            Vt[off] = uv.s[i];
        }
    }
    __syncthreads();
    f32x4 macc[4] = {};
    #pragma unroll
    for (int st = 0; st < 2; st++) {
        int c0 = st * 32 + g * 4;
        int rk = w * 16 + ln;   // dk row (B operand)
        uint2 klo = *(const uint2*)(&Kt[rk * 64 + vswz(rk, c0 >> 3) * 8 + (c0 & 7)]);
        uint2 khi = *(const uint2*)(&Kt[rk * 64 + vswz(rk, (c0 + 16) >> 3) * 8 + (c0 & 7)]);
        uint4 kc = make_uint4(klo.x, klo.y, khi.x, khi.y);
        bf16x8 bfrag = __builtin_bit_cast(bf16x8, kc);
        #pragma unroll
        for (int mt = 0; mt < 4; mt++) {
            int rv = mt * 16 + ln;  // dv row (A operand)
            uint2 lo = *(const uint2*)(&Vt[rv * 64 + vswz(rv, c0 >> 3) * 8 + (c0 & 7)]);
            uint2 hi = *(const uint2*)(&Vt[rv * 64 + vswz(rv, (c0 + 16) >> 3) * 8 + (c0 & 7)]);
            uint4 comb = make_uint4(lo.x, lo.y, hi.x, hi.y);
            bf16x8 afrag = __builtin_bit_cast(bf16x8, comb);
            macc[mt] = __builtin_amdgcn_mfma_f32_16x16x32_bf16(afrag, bfrag, macc[mt], 0, 0, 0);
        }
    }
    unsigned short* Mc = Mbuf + ((size_t)bh * 32 + c) * 4096;
    #pragma unroll
    for (int mt = 0; mt < 4; mt++)
        #pragma unroll
        for (int r = 0; r < 4; r++)
            Mc[(mt * 16 + g * 4 + r) * 64 + w * 16 + ln] = f2bf(macc[mt][r]);
}

// exclusive prefix over 32 chunks, IN PLACE (each thread owns its 4B slice)
__global__ __launch_bounds__(256) void k_prefix(unsigned short* __restrict__ Mbuf) {
    int bh = blockIdx.x >> 3, slice = blockIdx.x & 7;
    int base = slice * 512 + threadIdx.x * 2;
    unsigned short* M = Mbuf + (size_t)bh * 32 * 4096 + base;
    unsigned int v[32];
    #pragma unroll
    for (int c = 0; c < 32; c++) v[c] = *(const unsigned int*)(M + (size_t)c * 4096);
    float a0 = 0.f, a1 = 0.f;
    #pragma unroll
    for (int c = 0; c < 32; c++) {
        unsigned int pack = (unsigned int)f2bf(a0) | ((unsigned int)f2bf(a1) << 16);
        *(unsigned int*)(M + (size_t)c * 4096) = pack;
        a0 += bf2f((unsigned short)(v[c] & 0xFFFF));
        a1 += bf2f((unsigned short)(v[c] >> 16));
    }
}

__global__ __launch_bounds__(256) void k_attn2(const unsigned short* __restrict__ QKV,
                                               const unsigned short* __restrict__ Sbuf,
                                               const float* __restrict__ beta,
                                               unsigned short* __restrict__ attn) {
    __shared__ unsigned short Ks[64 * 64];   // diag K tile [key][dh], swizzled, scaled
    __shared__ unsigned short Vt[64 * 64];   // diag V^T [dv][key], vswz
    __shared__ unsigned short STs[64 * 64];  // S^T [dv][dk], swizzled row-major
    int qt = blockIdx.x, bh = blockIdx.y;
    int b = bh >> 4, h = bh & 15;
    int tid = threadIdx.x, w = tid >> 6, lane = tid & 63, g = lane >> 4, ln = lane & 15;
    int rowbase = b * 2048 + qt * 64;

    const unsigned short* Kg = QKV + 1024;
    const unsigned short* Vg = QKV + 2048;
    const unsigned short* Sg = Sbuf + ((size_t)bh * 32 + qt) * 4096;

    // ---- issue async S^T staging FIRST (gload_lds, inverse-swizzled source) ----
    #pragma unroll
    for (int cc = 0; cc < 2; cc++) {
        int c = tid + cc * 256;
        int r = c >> 3, psl = c & 7;
        int sl = psl ^ (r & 7);                   // involution: same XOR on store & read
        gload_lds16(Sg + r * 64 + sl * 8, &STs[(cc * 256 + w * 64) * 8]);
    }

    // Q fragments (raw); q-norm folded into output scale
    const unsigned short* Qrow = QKV + (size_t)(rowbase + w * 16 + ln) * 3072 + h * 64;
    u16x8 qu0 = *(const u16x8*)(Qrow + g * 8);
    u16x8 qu1 = *(const u16x8*)(Qrow + 32 + g * 8);
    bf16x8 qf[2];
    qf[0] = __builtin_bit_cast(bf16x8, qu0);
    qf[1] = __builtin_bit_cast(bf16x8, qu1);
    float ssq = 0.f;
    #pragma unroll
    for (int j = 0; j < 8; j++) {
        float v0 = bf2f(qu0[j]), v1 = bf2f(qu1[j]);
        ssq += v0 * v0 + v1 * v1;
    }
    ssq += __shfl_xor(ssq, 16, 64);
    ssq += __shfl_xor(ssq, 32, 64);
    float qscale = 1.f / fmaxf(sqrtf(ssq), 1e-12f);

    // ---- stage K (scaled by beta/||k||) and V^T (reg-staged) ----
    #pragma unroll
    for (int cc = 0; cc < 2; cc++) {
        int c = tid + cc * 256;
        int r = c >> 3, sl = c & 7;
        uint4 kd = *(const uint4*)(Kg + (size_t)(rowbase + r) * 3072 + h * 64 + sl * 8);
        union { uint4 q; unsigned short s[8]; } uk; uk.q = kd;
        float ssk = 0.f;
        #pragma unroll
        for (int i = 0; i < 8; i++) { float v = bf2f(uk.s[i]); ssk += v * v; }
        ssk += __shfl_xor(ssk, 1, 64);
        ssk += __shfl_xor(ssk, 2, 64);
        ssk += __shfl_xor(ssk, 4, 64);
        float ksc = beta[(rowbase + r) * 16 + h] / fmaxf(sqrtf(ssk), 1e-12f);
        #pragma unroll
        for (int i = 0; i < 8; i++) uk.s[i] = f2bf(bf2f(uk.s[i]) * ksc);
        *(uint4*)(&Ks[r * 64 + ((sl ^ (r & 7)) * 8)]) = uk.q;
        uint4 vd = *(const uint4*)(Vg + (size_t)(rowbase + r) * 3072 + h * 64 + sl * 8);
        union { uint4 q; unsigned short s[8]; } uv; uv.q = vd;
        #pragma unroll
        for (int i = 0; i < 8; i++) {
            int dh = sl * 8 + i;
            Vt[dh * 64 + vswz(dh, r >> 3) * 8 + (r & 7)] = uv.s[i];
        }
    }
    __syncthreads();

    f32x4 oacc[4] = {};

    // ---- part 1: O^T += S^T * Q^T ----
    #pragma unroll
    for (int st = 0; st < 2; st++)
        #pragma unroll
        for (int mt2 = 0; mt2 < 4; mt2++) {
            int r = mt2 * 16 + ln;
            int ps = (st * 4 + g) ^ (r & 7);
            bf16x8 a = *(const bf16x8*)(&STs[r * 64 + ps * 8]);
            oacc[mt2] = __builtin_amdgcn_mfma_f32_16x16x32_bf16(a, qf[st], oacc[mt2], 0, 0, 0);
        }

    // ---- part 2: diag tile S^T = K^b Q^T, mask, P^T -> PV ----
    f32x4 s[4] = {};
    #pragma unroll
    for (int st = 0; st < 2; st++)
        #pragma unroll
        for (int mt = 0; mt < 4; mt++) {
            int r = mt * 16 + ln;
            int ps = (st * 4 + g) ^ (r & 7);
            bf16x8 a = *(const bf16x8*)(&Ks[r * 64 + ps * 8]);
            s[mt] = __builtin_amdgcn_mfma_f32_16x16x32_bf16(a, qf[st], s[mt], 0, 0, 0);
        }
    {
        int qr = w * 16 + ln;
        #pragma unroll
        for (int mt = 0; mt < 4; mt++)
            #pragma unroll
            for (int r = 0; r < 4; r++)
                if (mt * 16 + g * 4 + r > qr) s[mt][r] = 0.f;
    }
    bf16x8 pf[2];
    #pragma unroll
    for (int st = 0; st < 2; st++) {
        u16x8 t;
        #pragma unroll
        for (int r = 0; r < 4; r++) {
            t[r]     = f2bf(s[2 * st][r]);
            t[4 + r] = f2bf(s[2 * st + 1][r]);
        }
        pf[st] = __builtin_bit_cast(bf16x8, t);
    }
    #pragma unroll
    for (int st = 0; st < 2; st++)
        #pragma unroll
        for (int mt2 = 0; mt2 < 4; mt2++) {
            int rv = mt2 * 16 + ln;
            int c0 = st * 32 + g * 4;
            uint2 lo = *(const uint2*)(&Vt[rv * 64 + vswz(rv, c0 >> 3) * 8 + (c0 & 7)]);
            uint2 hi = *(const uint2*)(&Vt[rv * 64 + vswz(rv, (c0 + 16) >> 3) * 8 + (c0 & 7)]);
            uint4 comb = make_uint4(lo.x, lo.y, hi.x, hi.y);
            bf16x8 a = __builtin_bit_cast(bf16x8, comb);
            oacc[mt2] = __builtin_amdgcn_mfma_f32_16x16x32_bf16(a, pf[st], oacc[mt2], 0, 0, 0);
        }
    __syncthreads();

    // ---- epilogue: apply qscale, transpose O^T via LDS, coalesced store ----
    {
        int qr = w * 16 + ln;
        #pragma unroll
        for (int mt2 = 0; mt2 < 4; mt2++)
            #pragma unroll
            for (int r = 0; r < 4; r++) {
                int dh = mt2 * 16 + g * 4 + r;
                Ks[qr * 64 + (dh ^ ((qr & 7) << 3))] = f2bf(oacc[mt2][r] * qscale);
            }
    }
    __syncthreads();
    #pragma unroll
    for (int cc = 0; cc < 2; cc++) {
        int c = tid + cc * 256;
        int r = c >> 3, sl = c & 7;
        uint4 d = *(const uint4*)(&Ks[r * 64 + ((sl ^ (r & 7)) * 8)]);
        *(uint4*)(attn + (size_t)(rowbase + r) * 1024 + h * 64 + sl * 8) = d;
    }
}

// ===================== launcher =====================
extern "C" void kernel_launch(void* const* d_in, const int* in_sizes, int n_in,
                              void* d_out, int out_size, void* d_ws, size_t ws_size,
                              hipStream_t stream) {
    const float* x  = (const float*)d_in[0];
    const float* Wq = (const float*)d_in[1];
    const float* Wk = (const float*)d_in[2];
    const float* Wv = (const float*)d_in[3];
    const float* Wo = (const float*)d_in[4];
    const float* Wb = (const float*)d_in[5];
    const float* bb = (const float*)d_in[6];
    float* out = (float*)d_out;

    char* ws = (char*)d_ws;
    unsigned short* xb    = (unsigned short*)(ws);                       // 8 MB; dead after QKV gemm
    unsigned short* Mbuf  = (unsigned short*)(ws);                       // 8 MB -- OVERLAYS xb
    unsigned short* Wqkvt = (unsigned short*)(ws + (8ull  << 20));       // 6 MB
    unsigned short* Wot   = (unsigned short*)(ws + (14ull << 20));       // 2 MB
    unsigned short* QKVb  = (unsigned short*)(ws + (16ull << 20));       // 24 MB [4096][3072]
    float*          beta  = (float*)         (ws + (40ull << 20));       // 256KB
    unsigned short* attn  = (unsigned short*)(ws + (41ull << 20));       // 8 MB [4096][1024]
    // total 49 MB of d_ws used

    k_prep0<<<5120, 256, 0, stream>>>(x, Wq, Wk, Wv, Wo, xb, Wqkvt, Wot);
    k_beta<<<1024, 256, 0, stream>>>(x, Wb, bb, beta);
    k_gemm_qkv<<<dim3(32, 24), 256, 0, stream>>>(xb, Wqkvt, QKVb);
    k_state<<<dim3(32, 32), 256, 0, stream>>>(QKVb, beta, Mbuf);   // xb dead from here
    k_prefix<<<256, 256, 0, stream>>>(Mbuf);                       // in-place exclusive prefix
    k_attn2<<<dim3(32, 32), 256, 0, stream>>>(QKVb, Mbuf, beta, attn);
    k_gemm_out<<<dim3(32, 16), 256, 0, stream>>>(attn, Wot, out);
}

// Round 10
// 172.988 us; speedup vs baseline: 1.0270x; 1.0270x over previous
//
#include <hip/hip_runtime.h>
#include <stdint.h>

#define DEV static __device__ __forceinline__

typedef __bf16 bf16x8 __attribute__((ext_vector_type(8)));
typedef unsigned short u16x8 __attribute__((ext_vector_type(8)));
typedef float f32x4 __attribute__((ext_vector_type(4)));

// ---- bf16 helpers (RNE) ----
DEV unsigned short f2bf(float f) {
    unsigned int u = __builtin_bit_cast(unsigned int, f);
    u = (u + 0x7FFFu + ((u >> 16) & 1u)) >> 16;
    return (unsigned short)u;
}
DEV float bf2f(unsigned short h) {
    unsigned int u = ((unsigned int)h) << 16;
    return __builtin_bit_cast(float, u);
}

// ---- async global->LDS, 16B per lane (wave-uniform LDS base + lane*16) ----
DEV void gload_lds16(const unsigned short* g, unsigned short* l) {
    __builtin_amdgcn_global_load_lds(
        (const __attribute__((address_space(1))) unsigned int*)g,
        (__attribute__((address_space(3))) unsigned int*)l, 16, 0, 0);
}

// ===================== fused prep: cvt | W transpose | beta =====================
// grid 6144: [0,4096) x fp32->bf16; [4096,5120) W transpose 64x64 tiles;
// [5120,6144) beta (one row/wave). LDS union 32KB -> 5 blocks/CU.
__global__ __launch_bounds__(256) void k_prep(
    const float* __restrict__ x, const float* __restrict__ Wq,
    const float* __restrict__ Wk, const float* __restrict__ Wv,
    const float* __restrict__ Wo, const float* __restrict__ Wb,
    const float* __restrict__ bb, unsigned short* __restrict__ xb,
    unsigned short* __restrict__ Wqkvt, unsigned short* __restrict__ Wot,
    float* __restrict__ beta) {
    __shared__ __align__(16) char smem[32768];
    int bid = blockIdx.x, tid = threadIdx.x;
    if (bid < 4096) {
        // ---- cvt: x fp32 -> bf16 ----
        int i = bid * 256 + tid;
        float4 v = ((const float4*)x)[i];
        ushort4 o;
        o.x = f2bf(v.x); o.y = f2bf(v.y); o.z = f2bf(v.z); o.w = f2bf(v.w);
        ((ushort4*)xb)[i] = o;
    } else if (bid < 5120) {
        // ---- weight transpose + convert: Wt[n][k] = bf16(W[k][n]), 64x64 tile ----
        float (*tile)[65] = (float(*)[65])smem;
        int idx = bid - 4096;
        int z = idx >> 8, rem = idx & 255;
        const float* W = (z == 0) ? Wq : (z == 1) ? Wk : (z == 2) ? Wv : Wo;
        int k0 = (rem & 15) * 64, n0 = (rem >> 4) * 64;
        int tx = tid & 63, ty = tid >> 6;
        #pragma unroll
        for (int r = 0; r < 64; r += 4)
            tile[ty + r][tx] = W[(size_t)(k0 + ty + r) * 1024 + n0 + tx];
        __syncthreads();
        #pragma unroll
        for (int r = 0; r < 64; r += 4) {
            float v = tile[tx][ty + r];           // = W[k0+tx][n0+ty+r]
            int n = n0 + ty + r, k = k0 + tx;
            if (z < 3) Wqkvt[(size_t)(z * 1024 + n) * 1024 + k] = f2bf(v);
            else       Wot[(size_t)n * 1024 + k] = f2bf(v);
        }
    } else {
        // ---- beta = sigmoid(x @ Wb + bb): WbT staged bf16, one row per wave ----
        unsigned short* WbT = (unsigned short*)smem;
        int bbl = bid - 5120;
        #pragma unroll
        for (int j = 0; j < 16; j++) {
            int idx4 = tid + 256 * j;
            float4 v = ((const float4*)Wb)[idx4];
            int i = idx4 >> 2;
            int h0 = (idx4 & 3) * 4;
            WbT[(h0 + 0) * 1024 + (i ^ ((h0 + 0) << 2))] = f2bf(v.x);
            WbT[(h0 + 1) * 1024 + (i ^ ((h0 + 1) << 2))] = f2bf(v.y);
            WbT[(h0 + 2) * 1024 + (i ^ ((h0 + 2) << 2))] = f2bf(v.z);
            WbT[(h0 + 3) * 1024 + (i ^ ((h0 + 3) << 2))] = f2bf(v.w);
        }
        __syncthreads();
        int w = tid >> 6, lane = tid & 63;
        int row = bbl * 4 + w;
        const float* xr = x + (size_t)row * 1024;
        float acc[16] = {};
        #pragma unroll
        for (int k = 0; k < 16; k++) {
            int i = lane + 64 * k;
            float xv = xr[i];
            #pragma unroll
            for (int h = 0; h < 16; h++)
                acc[h] += xv * bf2f(WbT[h * 1024 + (i ^ (h << 2))]);
        }
        #pragma unroll
        for (int h = 0; h < 16; h++) {
            #pragma unroll
            for (int m = 32; m; m >>= 1) acc[h] += __shfl_xor(acc[h], m, 64);
        }
        if (lane == 0) {
            #pragma unroll
            for (int h = 0; h < 16; h++)
                beta[row * 16 + h] = 1.f / (1.f + __expf(-(acc[h] + bb[h])));
        }
    }
}

// ===================== QKV GEMM: 128x128 tile, BK=64, gload_lds staging =====================
__global__ __launch_bounds__(256) void k_gemm_qkv(const unsigned short* __restrict__ A,
                                                  const unsigned short* __restrict__ Bt,
                                                  unsigned short* __restrict__ C) {
    __shared__ unsigned short As[128 * 64];
    __shared__ unsigned short Bs[128 * 64];
    int m0 = blockIdx.x * 128, n0 = blockIdx.y * 128;
    int tid = threadIdx.x;
    int w = tid >> 6, lane = tid & 63, g = lane >> 4, ln = lane & 15;
    int wr = w >> 1, wc = w & 1;
    f32x4 acc[4][4] = {};
    for (int k0 = 0; k0 < 1024; k0 += 64) {
        #pragma unroll
        for (int cc = 0; cc < 4; cc++) {
            int base = (w * 4 + cc) * 64;          // wave-uniform chunk base (0..1023)
            int chunk = base + lane;
            int row = chunk >> 3, ps = chunk & 7;
            int sl = (ps - (row >> 1)) & 7;        // inverse swizzle on source
            gload_lds16(A + (size_t)(m0 + row) * 1024 + k0 + sl * 8, &As[base * 8]);
            gload_lds16(Bt + (size_t)(n0 + row) * 1024 + k0 + sl * 8, &Bs[base * 8]);
        }
        __syncthreads();
        #pragma unroll
        for (int s = 0; s < 2; s++) {
            bf16x8 af[4], bfr[4];
            #pragma unroll
            for (int mi = 0; mi < 4; mi++) {
                int row = wr * 64 + mi * 16 + ln;
                int ps = (s * 4 + g + (row >> 1)) & 7;
                af[mi] = *(const bf16x8*)(&As[row * 64 + ps * 8]);
            }
            #pragma unroll
            for (int ni = 0; ni < 4; ni++) {
                int row = wc * 64 + ni * 16 + ln;
                int ps = (s * 4 + g + (row >> 1)) & 7;
                bfr[ni] = *(const bf16x8*)(&Bs[row * 64 + ps * 8]);
            }
            #pragma unroll
            for (int mi = 0; mi < 4; mi++)
                #pragma unroll
                for (int ni = 0; ni < 4; ni++)
                    acc[mi][ni] = __builtin_amdgcn_mfma_f32_16x16x32_bf16(
                        af[mi], bfr[ni], acc[mi][ni], 0, 0, 0);
        }
        __syncthreads();
    }
    #pragma unroll
    for (int mi = 0; mi < 4; mi++)
        #pragma unroll
        for (int ni = 0; ni < 4; ni++)
            #pragma unroll
            for (int r = 0; r < 4; r++) {
                int row = m0 + wr * 64 + mi * 16 + g * 4 + r;
                int col = n0 + wc * 64 + ni * 16 + ln;
                C[(size_t)row * 3072 + col] = f2bf(acc[mi][ni][r]);
            }
}

// ===================== out GEMM: 128x64 tile, BK=64, fp32 out =====================
__global__ __launch_bounds__(256) void k_gemm_out(const unsigned short* __restrict__ A,
                                                  const unsigned short* __restrict__ Bt,
                                                  float* __restrict__ C) {
    __shared__ unsigned short As[128 * 64];
    __shared__ unsigned short Bs[64 * 64];
    int m0 = blockIdx.x * 128, n0 = blockIdx.y * 64;
    int tid = threadIdx.x;
    int w = tid >> 6, lane = tid & 63, g = lane >> 4, ln = lane & 15;
    int wr = w >> 1, wc = w & 1;
    f32x4 acc[4][2] = {};
    for (int k0 = 0; k0 < 1024; k0 += 64) {
        #pragma unroll
        for (int i = 0; i < 6; i++) {
            int base = w * 384 + i * 64;           // wave-uniform
            int chunk = base + lane;
            if (base < 1024) {                     // A chunks 0..1023
                int row = chunk >> 3, ps = chunk & 7;
                int sl = (ps - (row >> 1)) & 7;
                gload_lds16(A + (size_t)(m0 + row) * 1024 + k0 + sl * 8, &As[base * 8]);
            } else {                               // B chunks 0..511
                int bc = chunk - 1024;
                int row = bc >> 3, ps = bc & 7;
                int sl = (ps - (row >> 1)) & 7;
                gload_lds16(Bt + (size_t)(n0 + row) * 1024 + k0 + sl * 8, &Bs[(base - 1024) * 8]);
            }
        }
        __syncthreads();
        #pragma unroll
        for (int s = 0; s < 2; s++) {
            bf16x8 af[4], bfr[2];
            #pragma unroll
            for (int mi = 0; mi < 4; mi++) {
                int row = wr * 64 + mi * 16 + ln;
                int ps = (s * 4 + g + (row >> 1)) & 7;
                af[mi] = *(const bf16x8*)(&As[row * 64 + ps * 8]);
            }
            #pragma unroll
            for (int ni = 0; ni < 2; ni++) {
                int row = wc * 32 + ni * 16 + ln;
                int ps = (s * 4 + g + (row >> 1)) & 7;
                bfr[ni] = *(const bf16x8*)(&Bs[row * 64 + ps * 8]);
            }
            #pragma unroll
            for (int mi = 0; mi < 4; mi++)
                #pragma unroll
                for (int ni = 0; ni < 2; ni++)
                    acc[mi][ni] = __builtin_amdgcn_mfma_f32_16x16x32_bf16(
                        af[mi], bfr[ni], acc[mi][ni], 0, 0, 0);
        }
        __syncthreads();
    }
    #pragma unroll
    for (int mi = 0; mi < 4; mi++)
        #pragma unroll
        for (int ni = 0; ni < 2; ni++)
            #pragma unroll
            for (int r = 0; r < 4; r++) {
                int row = m0 + wr * 64 + mi * 16 + g * 4 + r;
                int col = n0 + wc * 32 + ni * 16 + ln;
                C[(size_t)row * 1024 + col] = acc[mi][ni][r];
            }
}

// ===================== chunked linear attention =====================
DEV int vswz(int dh, int ks) { return (ks ^ (dh & 7) ^ ((dh >> 3) & 7)) & 7; }

// k_state: M^T_c = V^T (beta/||k|| * K); ALSO writes normalized beta*k^ back to
// QKV in place (each block owns its chunk x head region exclusively).
__global__ __launch_bounds__(256) void k_state(unsigned short* __restrict__ QKV,
                                               const float* __restrict__ beta,
                                               unsigned short* __restrict__ Mbuf) {
    __shared__ unsigned short Kt[64 * 64];  // [dk][t], vswz, scaled by beta/||k||
    __shared__ unsigned short Vt[64 * 64];  // [dv][t], vswz
    int c = blockIdx.x, bh = blockIdx.y;
    int b = bh >> 4, h = bh & 15;
    int tid = threadIdx.x, w = tid >> 6, lane = tid & 63, g = lane >> 4, ln = lane & 15;
    int row0 = b * 2048 + c * 64;
    unsigned short* Kg = QKV + 1024;
    const unsigned short* Vg = QKV + 2048;
    #pragma unroll
    for (int cc = 0; cc < 2; cc++) {
        int ci = tid + cc * 256;
        int r = ci >> 3, sl = ci & 7;   // 8 consecutive lanes share key row r
        uint4 kd = *(const uint4*)(Kg + (size_t)(row0 + r) * 3072 + h * 64 + sl * 8);
        uint4 vd = *(const uint4*)(Vg + (size_t)(row0 + r) * 3072 + h * 64 + sl * 8);
        union { uint4 q; unsigned short s[8]; } uk, uv;
        uk.q = kd; uv.q = vd;
        float ssk = 0.f;
        #pragma unroll
        for (int i = 0; i < 8; i++) { float v = bf2f(uk.s[i]); ssk += v * v; }
        ssk += __shfl_xor(ssk, 1, 64);
        ssk += __shfl_xor(ssk, 2, 64);
        ssk += __shfl_xor(ssk, 4, 64);
        float ksc = beta[(row0 + r) * 16 + h] / fmaxf(sqrtf(ssk), 1e-12f);
        #pragma unroll
        for (int i = 0; i < 8; i++) uk.s[i] = f2bf(bf2f(uk.s[i]) * ksc);
        // write back normalized beta*k^ (consumed by k_attn2's diag tile)
        *(uint4*)(Kg + (size_t)(row0 + r) * 3072 + h * 64 + sl * 8) = uk.q;
        #pragma unroll
        for (int i = 0; i < 8; i++) {
            int dh = sl * 8 + i;
            int off = dh * 64 + vswz(dh, r >> 3) * 8 + (r & 7);
            Kt[off] = uk.s[i];
            Vt[off] = uv.s[i];
        }
    }
    __syncthreads();
    f32x4 macc[4] = {};
    #pragma unroll
    for (int st = 0; st < 2; st++) {
        int c0 = st * 32 + g * 4;
        int rk = w * 16 + ln;   // dk row (B operand)
        uint2 klo = *(const uint2*)(&Kt[rk * 64 + vswz(rk, c0 >> 3) * 8 + (c0 & 7)]);
        uint2 khi = *(const uint2*)(&Kt[rk * 64 + vswz(rk, (c0 + 16) >> 3) * 8 + (c0 & 7)]);
        uint4 kc = make_uint4(klo.x, klo.y, khi.x, khi.y);
        bf16x8 bfrag = __builtin_bit_cast(bf16x8, kc);
        #pragma unroll
        for (int mt = 0; mt < 4; mt++) {
            int rv = mt * 16 + ln;  // dv row (A operand)
            uint2 lo = *(const uint2*)(&Vt[rv * 64 + vswz(rv, c0 >> 3) * 8 + (c0 & 7)]);
            uint2 hi = *(const uint2*)(&Vt[rv * 64 + vswz(rv, (c0 + 16) >> 3) * 8 + (c0 & 7)]);
            uint4 comb = make_uint4(lo.x, lo.y, hi.x, hi.y);
            bf16x8 afrag = __builtin_bit_cast(bf16x8, comb);
            macc[mt] = __builtin_amdgcn_mfma_f32_16x16x32_bf16(afrag, bfrag, macc[mt], 0, 0, 0);
        }
    }
    unsigned short* Mc = Mbuf + ((size_t)bh * 32 + c) * 4096;
    #pragma unroll
    for (int mt = 0; mt < 4; mt++)
        #pragma unroll
        for (int r = 0; r < 4; r++)
            Mc[(mt * 16 + g * 4 + r) * 64 + w * 16 + ln] = f2bf(macc[mt][r]);
}

// exclusive prefix over 32 chunks, IN PLACE (each thread owns its 4B slice)
__global__ __launch_bounds__(256) void k_prefix(unsigned short* __restrict__ Mbuf) {
    int bh = blockIdx.x >> 3, slice = blockIdx.x & 7;
    int base = slice * 512 + threadIdx.x * 2;
    unsigned short* M = Mbuf + (size_t)bh * 32 * 4096 + base;
    unsigned int v[32];
    #pragma unroll
    for (int c = 0; c < 32; c++) v[c] = *(const unsigned int*)(M + (size_t)c * 4096);
    float a0 = 0.f, a1 = 0.f;
    #pragma unroll
    for (int c = 0; c < 32; c++) {
        unsigned int pack = (unsigned int)f2bf(a0) | ((unsigned int)f2bf(a1) << 16);
        *(unsigned int*)(M + (size_t)c * 4096) = pack;
        a0 += bf2f((unsigned short)(v[c] & 0xFFFF));
        a1 += bf2f((unsigned short)(v[c] >> 16));
    }
}

// k_attn2: K (pre-normalized by k_state) and S^T staged ASYNC via gload_lds with
// the XOR involution on the source; V^T reg-staged (transpose). Q-norm in epilogue.
__global__ __launch_bounds__(256) void k_attn2(const unsigned short* __restrict__ QKV,
                                               const unsigned short* __restrict__ Sbuf,
                                               unsigned short* __restrict__ attn) {
    __shared__ unsigned short Ks[64 * 64];   // diag K tile [key][dh], XOR-swizzled
    __shared__ unsigned short Vt[64 * 64];   // diag V^T [dv][key], vswz
    __shared__ unsigned short STs[64 * 64];  // S^T [dv][dk], XOR-swizzled
    int qt = blockIdx.x, bh = blockIdx.y;
    int b = bh >> 4, h = bh & 15;
    int tid = threadIdx.x, w = tid >> 6, lane = tid & 63, g = lane >> 4, ln = lane & 15;
    int rowbase = b * 2048 + qt * 64;

    const unsigned short* Kg = QKV + 1024;
    const unsigned short* Vg = QKV + 2048;
    const unsigned short* Sg = Sbuf + ((size_t)bh * 32 + qt) * 4096;

    // ---- issue ALL async staging first (S^T and K), inverse-swizzled sources ----
    #pragma unroll
    for (int cc = 0; cc < 2; cc++) {
        int c = tid + cc * 256;
        int r = c >> 3, psl = c & 7;
        int sl = psl ^ (r & 7);                   // involution: same XOR on store & read
        gload_lds16(Sg + r * 64 + sl * 8, &STs[(cc * 256 + w * 64) * 8]);
        gload_lds16(Kg + (size_t)(rowbase + r) * 3072 + h * 64 + sl * 8,
                    &Ks[(cc * 256 + w * 64) * 8]);
    }

    // Q fragments (raw); q-norm folded into output scale
    const unsigned short* Qrow = QKV + (size_t)(rowbase + w * 16 + ln) * 3072 + h * 64;
    u16x8 qu0 = *(const u16x8*)(Qrow + g * 8);
    u16x8 qu1 = *(const u16x8*)(Qrow + 32 + g * 8);
    bf16x8 qf[2];
    qf[0] = __builtin_bit_cast(bf16x8, qu0);
    qf[1] = __builtin_bit_cast(bf16x8, qu1);
    float ssq = 0.f;
    #pragma unroll
    for (int j = 0; j < 8; j++) {
        float v0 = bf2f(qu0[j]), v1 = bf2f(qu1[j]);
        ssq += v0 * v0 + v1 * v1;
    }
    ssq += __shfl_xor(ssq, 16, 64);
    ssq += __shfl_xor(ssq, 32, 64);
    float qscale = 1.f / fmaxf(sqrtf(ssq), 1e-12f);

    // ---- stage V^T (reg-staged transpose) ----
    #pragma unroll
    for (int cc = 0; cc < 2; cc++) {
        int c = tid + cc * 256;
        int r = c >> 3, sl = c & 7;
        uint4 vd = *(const uint4*)(Vg + (size_t)(rowbase + r) * 3072 + h * 64 + sl * 8);
        union { uint4 q; unsigned short s[8]; } uv; uv.q = vd;
        #pragma unroll
        for (int i = 0; i < 8; i++) {
            int dh = sl * 8 + i;
            Vt[dh * 64 + vswz(dh, r >> 3) * 8 + (r & 7)] = uv.s[i];
        }
    }
    __syncthreads();

    f32x4 oacc[4] = {};

    // ---- part 1: O^T += S^T * Q^T ----
    #pragma unroll
    for (int st = 0; st < 2; st++)
        #pragma unroll
        for (int mt2 = 0; mt2 < 4; mt2++) {
            int r = mt2 * 16 + ln;
            int ps = (st * 4 + g) ^ (r & 7);
            bf16x8 a = *(const bf16x8*)(&STs[r * 64 + ps * 8]);
            oacc[mt2] = __builtin_amdgcn_mfma_f32_16x16x32_bf16(a, qf[st], oacc[mt2], 0, 0, 0);
        }

    // ---- part 2: diag tile S^T = (beta k^) Q^T, mask, P^T -> PV ----
    f32x4 s[4] = {};
    #pragma unroll
    for (int st = 0; st < 2; st++)
        #pragma unroll
        for (int mt = 0; mt < 4; mt++) {
            int r = mt * 16 + ln;
            int ps = (st * 4 + g) ^ (r & 7);
            bf16x8 a = *(const bf16x8*)(&Ks[r * 64 + ps * 8]);
            s[mt] = __builtin_amdgcn_mfma_f32_16x16x32_bf16(a, qf[st], s[mt], 0, 0, 0);
        }
    {
        int qr = w * 16 + ln;
        #pragma unroll
        for (int mt = 0; mt < 4; mt++)
            #pragma unroll
            for (int r = 0; r < 4; r++)
                if (mt * 16 + g * 4 + r > qr) s[mt][r] = 0.f;
    }
    bf16x8 pf[2];
    #pragma unroll
    for (int st = 0; st < 2; st++) {
        u16x8 t;
        #pragma unroll
        for (int r = 0; r < 4; r++) {
            t[r]     = f2bf(s[2 * st][r]);
            t[4 + r] = f2bf(s[2 * st + 1][r]);
        }
        pf[st] = __builtin_bit_cast(bf16x8, t);
    }
    #pragma unroll
    for (int st = 0; st < 2; st++)
        #pragma unroll
        for (int mt2 = 0; mt2 < 4; mt2++) {
            int rv = mt2 * 16 + ln;
            int c0 = st * 32 + g * 4;
            uint2 lo = *(const uint2*)(&Vt[rv * 64 + vswz(rv, c0 >> 3) * 8 + (c0 & 7)]);
            uint2 hi = *(const uint2*)(&Vt[rv * 64 + vswz(rv, (c0 + 16) >> 3) * 8 + (c0 & 7)]);
            uint4 comb = make_uint4(lo.x, lo.y, hi.x, hi.y);
            bf16x8 a = __builtin_bit_cast(bf16x8, comb);
            oacc[mt2] = __builtin_amdgcn_mfma_f32_16x16x32_bf16(a, pf[st], oacc[mt2], 0, 0, 0);
        }
    __syncthreads();

    // ---- epilogue: apply qscale, transpose O^T via LDS, coalesced store ----
    {
        int qr = w * 16 + ln;
        #pragma unroll
        for (int mt2 = 0; mt2 < 4; mt2++)
            #pragma unroll
            for (int r = 0; r < 4; r++) {
                int dh = mt2 * 16 + g * 4 + r;
                Ks[qr * 64 + (dh ^ ((qr & 7) << 3))] = f2bf(oacc[mt2][r] * qscale);
            }
    }
    __syncthreads();
    #pragma unroll
    for (int cc = 0; cc < 2; cc++) {
        int c = tid + cc * 256;
        int r = c >> 3, sl = c & 7;
        uint4 d = *(const uint4*)(&Ks[r * 64 + ((sl ^ (r & 7)) * 8)]);
        *(uint4*)(attn + (size_t)(rowbase + r) * 1024 + h * 64 + sl * 8) = d;
    }
}

// ===================== launcher =====================
extern "C" void kernel_launch(void* const* d_in, const int* in_sizes, int n_in,
                              void* d_out, int out_size, void* d_ws, size_t ws_size,
                              hipStream_t stream) {
    const float* x  = (const float*)d_in[0];
    const float* Wq = (const float*)d_in[1];
    const float* Wk = (const float*)d_in[2];
    const float* Wv = (const float*)d_in[3];
    const float* Wo = (const float*)d_in[4];
    const float* Wb = (const float*)d_in[5];
    const float* bb = (const float*)d_in[6];
    float* out = (float*)d_out;

    char* ws = (char*)d_ws;
    unsigned short* xb    = (unsigned short*)(ws);                       // 8 MB; dead after QKV gemm
    unsigned short* Mbuf  = (unsigned short*)(ws);                       // 8 MB -- OVERLAYS xb
    unsigned short* Wqkvt = (unsigned short*)(ws + (8ull  << 20));       // 6 MB
    unsigned short* Wot   = (unsigned short*)(ws + (14ull << 20));       // 2 MB
    unsigned short* QKVb  = (unsigned short*)(ws + (16ull << 20));       // 24 MB [4096][3072]
    float*          beta  = (float*)         (ws + (40ull << 20));       // 256KB
    unsigned short* attn  = (unsigned short*)(ws + (41ull << 20));       // 8 MB [4096][1024]
    // total 49 MB of d_ws used

    k_prep<<<6144, 256, 0, stream>>>(x, Wq, Wk, Wv, Wo, Wb, bb, xb, Wqkvt, Wot, beta);
    k_gemm_qkv<<<dim3(32, 24), 256, 0, stream>>>(xb, Wqkvt, QKVb);
    k_state<<<dim3(32, 32), 256, 0, stream>>>(QKVb, beta, Mbuf);   // xb dead from here
    k_prefix<<<256, 256, 0, stream>>>(Mbuf);                       // in-place exclusive prefix
    k_attn2<<<dim3(32, 32), 256, 0, stream>>>(QKVb, Mbuf, attn);
    k_gemm_out<<<dim3(32, 16), 256, 0, stream>>>(attn, Wot, out);
}